// Round 6
// baseline (183.912 us; speedup 1.0000x reference)
//
#include <hip/hip_runtime.h>
#include <math.h>

// ---------------------------------------------------------------------------
// FPSANConv2d: out = conv3x3(x, Qt(w)) + b + sigmoid(gate)*(conv3x3(x, Qt(w_child)) + b_child)
// Fused: W_eff = Qt(w) + g*Qt(w_child) (bf16), b_eff = b + g*b_child, ONE conv.
//
// Round 11:
//   (a) conv: 256-thr blocks, LDS cut to EXACTLY 81,920 B -> 2 blocks/CU, so
//       one block's A-staging (global loads + f2bf) hides under the other's
//       MFMA tap loop. A stores interior px only (65,536 B); pad px=0/129
//       handled by per-lane address redirect + cndmask-to-zero (only lanes
//       pb==0 @mf=0 and pb==81 @mf=3 ever touch pads). B ping-pong as R9.
//   (b) prep: k1+k2 fused into ONE kernel; all 144 blocks redundantly compute
//       the full f64 |w| sums in a FIXED order (bit-identical across blocks &
//       runs -> deterministic), then quantize their 256-elem slice.
// ---------------------------------------------------------------------------

typedef __attribute__((ext_vector_type(8))) short short8;   // 8 bf16 (4 VGPRs)
typedef __attribute__((ext_vector_type(4))) float float4v;  // MFMA C/D frag

__device__ inline unsigned short f2bf(float f) {
  union { float f; unsigned u; } v; v.f = f;
  unsigned u = v.u;
  return (unsigned short)((u + 0x7FFFu + ((u >> 16) & 1u)) >> 16);  // RNE
}

// ---- prep: deterministic redundant reduce + ternary quant + gate combine ----
// 144 blocks x 256 thr. Every block computes the SAME f64 sums (fixed order:
// thread t chains i = t, t+256, ...; wave shfl tree; 4-wave LDS sum) ->
// scale identical bitwise across blocks; then each block quantizes its slice.
__global__ __launch_bounds__(256) void prep(
    const float* __restrict__ w, const float* __restrict__ wc,
    const float* __restrict__ b, const float* __restrict__ bc,
    const float* __restrict__ gate,
    unsigned short* __restrict__ wq, float* __restrict__ beff) {
  const int tid = threadIdx.x;
  double a = 0.0, c = 0.0;
  for (int i = tid; i < 36864; i += 256) {
    a += (double)fabsf(w[i]);
    c += (double)fabsf(wc[i]);
  }
#pragma unroll
  for (int off = 32; off > 0; off >>= 1) {
    a += __shfl_down(a, off);
    c += __shfl_down(c, off);
  }
  __shared__ double sa[4], sc[4];
  const int wv = tid >> 6;
  if ((tid & 63) == 0) { sa[wv] = a; sc[wv] = c; }
  __syncthreads();
  const double ta = sa[0] + sa[1] + sa[2] + sa[3];
  const double tc = sc[0] + sc[1] + sc[2] + sc[3];
  const float sw = fmaxf((float)(ta * (1.0 / 36864.0)), 1e-5f);
  const float scl = fmaxf((float)(tc * (1.0 / 36864.0)), 1e-5f);
  const float g = 1.0f / (1.0f + expf(-gate[0]));
  const int idx = blockIdx.x * 256 + tid;  // (tap, oc, ci)
  const int tap = idx >> 12;
  const int oc = (idx >> 6) & 63;
  const int ci = idx & 63;
  const int src = oc * 576 + ci * 9 + tap;  // OIHW flat
  float q1 = fminf(1.f, fmaxf(-1.f, rintf(w[src] / sw))) * sw;
  float q2 = fminf(1.f, fmaxf(-1.f, rintf(wc[src] / scl))) * scl;
  wq[idx] = f2bf(q1 + g * q2);
  if (idx < 64) beff[idx] = b[idx] + g * bc[idx];
}

// ---- conv: NCHW f32 -> LDS bf16 staging + implicit-GEMM MFMA ----
// Block: 256 thr = 4 waves, 2 output rows x 128 px x 64 oc. Wave = 64px x 64oc.
// LDS 81,920 B total = EXACTLY 2 blocks per 160 KiB CU:
//   A: 4 rows x 128 interior px x 8 chunks x 16B = 65,536 B.
//      chunk(r, px, c) at slot (r*128 + px-1)*8 + (c ^ (px&7)), px in 1..128.
//      Pads: only px=0 (lane pb==0, mf=0) and px=129 (lane pb==81, mf=3) are
//      ever read -> redirect to a valid slot, cndmask fragment to 0.
//   B: 2 x 8,192 B ping-pong, slot oc*8 + (c ^ (oc&7)); staged 1 tap ahead
//      (global->reg at tap start, ds_write after MFMAs, 1 barrier per tap).
// XCD-ownership: XCD (bid&7) owns images 2*xcd, 2*xcd+1 (halo stays in 1 L2).
__global__ __launch_bounds__(256, 2) void conv_fused(
    const float* __restrict__ x, const unsigned short* __restrict__ wq,
    const float* __restrict__ beff, float* __restrict__ out) {
  extern __shared__ __align__(16) char smem[];  // 81,920 B
  char* Abase = smem;                  // 4096 chunks
  char* Bbase = smem + 65536;          // 2 x 512 chunks

  const int bid = blockIdx.x;          // 1024 blocks
  const int xcd = bid & 7;
  const int u = bid >> 3;              // 0..127
  const int n = xcd * 2 + (u >> 6);    // image
  const int h0 = (u & 63) * 2;         // output rows h0, h0+1
  const int tid = threadIdx.x;
  const int lane = tid & 63;
  const int wv = tid >> 6;             // 0..3
  const int rw = wv >> 1;              // output row within block (0/1)
  const int pxh = (wv & 1) * 64;       // pixel half
  const int ln15 = lane & 15;
  const int lq = lane >> 4;            // 16B ci-chunk (0..3)

  const float* xn = x + (size_t)n * (64 * 16384);

  // ---- B tap-0: 32B/thread coalesced global load (issued early) ----
  const short8 b0a = *(const short8*)(wq + tid * 16);
  const short8 b0b = *(const short8*)(wq + tid * 16 + 8);

  // ---- A staging: 16 passes x 2 wave-uniform (r,c)-combos x 128 px ----
  const int pxc = tid & 127;           // source col 0..127 (padded px = pxc+1)
  const int hi = tid >> 7;             // 0..1 (wave-uniform)
#pragma unroll 4
  for (int pass = 0; pass < 16; ++pass) {
    const int k = pass * 2 + hi;       // 0..31
    const int r = k >> 3;              // LDS row 0..3
    const int c = k & 7;               // ci chunk 0..7
    const int h = h0 + r - 1;          // source row, -1..128
    short8 v = (short8)0;
    if ((unsigned)h < 128u) {          // wave-uniform
      const float* sp = xn + c * 8 * 16384 + h * 128 + pxc;
      v[0] = (short)f2bf(sp[0 * 16384]);
      v[1] = (short)f2bf(sp[1 * 16384]);
      v[2] = (short)f2bf(sp[2 * 16384]);
      v[3] = (short)f2bf(sp[3 * 16384]);
      v[4] = (short)f2bf(sp[4 * 16384]);
      v[5] = (short)f2bf(sp[5 * 16384]);
      v[6] = (short)f2bf(sp[6 * 16384]);
      v[7] = (short)f2bf(sp[7 * 16384]);
    }
    const int slot = ((r * 128 + pxc) << 3) + (c ^ ((pxc + 1) & 7));
    *(short8*)(Abase + (slot << 4)) = v;
  }

  // ---- B tap-0 swizzled LDS write (2 chunks/thread) ----
  const int g0 = tid * 2;              // chunk 0..511 (even)
  const int oc0 = g0 >> 3;
  const int c0 = g0 & 7;               // even
  const int bs0 = (oc0 << 3) + (c0 ^ (oc0 & 7));
  const int bs1 = (oc0 << 3) + ((c0 + 1) ^ (oc0 & 7));
  *(short8*)(Bbase + (bs0 << 4)) = b0a;
  *(short8*)(Bbase + (bs1 << 4)) = b0b;
  __syncthreads();

  float4v acc[4][4] = {};  // [mf][qd]

#pragma unroll
  for (int tap = 0; tap < 9; ++tap) {
    const int cb = tap & 1;
    // issue next-tap B global load FIRST (hidden under this tap's MFMAs)
    short8 bta, btb;
    if (tap < 8) {
      bta = *(const short8*)(wq + (tap + 1) * 4096 + tid * 16);
      btb = *(const short8*)(wq + (tap + 1) * 4096 + tid * 16 + 8);
    }

    const int dh = tap / 3;
    const int dw = tap - dh * 3;
    const int r = rw + dh;             // 0..3
    const int pb = pxh + ln15 + dw;    // padded px for mf=0 (0..81)
    const bool p0 = (pb == 0);         // pad read only at mf=0
    const bool p129 = (pb == 81);      // pad read only at mf=3 (px=129)
    const int a0 = (((r * 128 + pb - 1) << 3) + (lq ^ (pb & 7))) << 4;
    const int off0 = p0 ? 2048 : 0;    // redirect to px=16 (valid), zeroed after
    const int off3 = p129 ? 4096 : 6144;  // redirect to px=pb+32, zeroed after

    short8 Ab[2][4], Bb[2][4];
#pragma unroll
    for (int cc = 0; cc < 2; ++cc) {   // ci chunk lq vs lq+4: byte addr ^64
      const int ax = a0 ^ (cc << 6);
      Ab[cc][0] = *(const short8*)(Abase + (ax + off0));
      Ab[cc][1] = *(const short8*)(Abase + (ax + 2048));
      Ab[cc][2] = *(const short8*)(Abase + (ax + 4096));
      Ab[cc][3] = *(const short8*)(Abase + (ax + off3));
      if (p0) Ab[cc][0] = (short8)0;
      if (p129) Ab[cc][3] = (short8)0;
    }
#pragma unroll
    for (int qd = 0; qd < 4; ++qd) {
      const int oc8 = ((qd << 4) + ln15) << 3;  // oc*8
      const int k7 = ln15 & 7;                  // oc&7
      Bb[0][qd] = *(const short8*)(Bbase + (cb << 13) + ((oc8 + (lq ^ k7)) << 4));
      Bb[1][qd] = *(const short8*)(Bbase + (cb << 13) + ((oc8 + ((lq + 4) ^ k7)) << 4));
    }

    __builtin_amdgcn_s_setprio(1);
#pragma unroll
    for (int cc2 = 0; cc2 < 2; ++cc2)
#pragma unroll
      for (int mf = 0; mf < 4; ++mf)
#pragma unroll
        for (int qd = 0; qd < 4; ++qd)
          acc[mf][qd] = __builtin_amdgcn_mfma_f32_16x16x32_bf16(
              Ab[cc2][mf], Bb[cc2][qd], acc[mf][qd], 0, 0, 0);
    __builtin_amdgcn_s_setprio(0);

    if (tap < 8) {
      // write next-tap B to the other buffer: it was last READ during tap-1,
      // whose trailing barrier already passed; readers of it wait on the
      // barrier below. Race-free (R9-verified scheme).
      char* bb = Bbase + ((cb ^ 1) << 13);
      *(short8*)(bb + (bs0 << 4)) = bta;
      *(short8*)(bb + (bs1 << 4)) = btb;
      __syncthreads();
    }
  }

  // ---- epilogue: C/D layout col=lane&15 (oc), row=(lane>>4)*4+reg (pixel) ----
  const int rq = lane >> 4;
  float bias[4];
#pragma unroll
  for (int q = 0; q < 4; ++q) bias[q] = beff[q * 16 + ln15];
#pragma unroll
  for (int mf = 0; mf < 4; ++mf) {
#pragma unroll
    for (int qd = 0; qd < 4; ++qd) {
      float4v v = acc[mf][qd] + bias[qd];
      int oc = qd * 16 + ln15;
      float* op = out + (((n * 64 + oc) * 128 + h0 + rw) * 128 + pxh + mf * 16 + rq * 4);
      *(float4v*)op = v;
    }
  }
}

extern "C" void kernel_launch(void* const* d_in, const int* in_sizes, int n_in,
                              void* d_out, int out_size, void* d_ws, size_t ws_size,
                              hipStream_t stream) {
  const float* x = (const float*)d_in[0];
  const float* w = (const float*)d_in[1];
  const float* b = (const float*)d_in[2];
  const float* wc = (const float*)d_in[3];
  const float* bc = (const float*)d_in[4];
  const float* gate = (const float*)d_in[5];

  // ws: wq bf16[36864]=73728B | beff f32[64] @73728
  unsigned short* wq = (unsigned short*)d_ws;
  float* beff = (float*)((char*)d_ws + 73728);

  prep<<<144, 256, 0, stream>>>(w, wc, b, bc, gate, wq, beff);
  conv_fused<<<1024, 256, 81920, stream>>>(x, wq, beff, (float*)d_out);
}

// Round 7
// 143.964 us; speedup vs baseline: 1.2775x; 1.2775x over previous
//
#include <hip/hip_runtime.h>
#include <math.h>

// ---------------------------------------------------------------------------
// FPSANConv2d: out = conv3x3(x, Qt(w)) + b + sigmoid(gate)*(conv3x3(x, Qt(w_child)) + b_child)
// Fused: W_eff = Qt(w) + g*Qt(w_child) (bf16), b_eff = b + g*b_child, ONE conv.
//
// Round 12:
//   prep: R11's serial 144-iter chain (59.9us, 21GB/s) -> batched float4
//     loads (8 in flight) + 4 independent f64 accumulators, fixed order
//     (bit-identical across blocks/runs). Predict ~4us.
//   conv: LDS 81,920 -> 73,728 B (single B buffer + 2 barriers/tap) so
//     2 blocks genuinely co-reside per CU (147,456 <= 163,840 w/ slack);
//     B prefetch issued AFTER barrier#1 so the syncthreads vmcnt-drain
//     doesn't expose L2 latency (covered by the MFMA cluster).
//     Staging restructured into 4 groups x {issue 32 loads -> convert+write}
//     to force a deep VMEM pipeline (R11's VGPR=92 proved it wasn't).
// ---------------------------------------------------------------------------

typedef __attribute__((ext_vector_type(8))) short short8;   // 8 bf16 (4 VGPRs)
typedef __attribute__((ext_vector_type(4))) float float4v;  // MFMA C/D frag

__device__ inline unsigned short f2bf(float f) {
  union { float f; unsigned u; } v; v.f = f;
  unsigned u = v.u;
  return (unsigned short)((u + 0x7FFFu + ((u >> 16) & 1u)) >> 16);  // RNE
}

// ---- prep: deterministic redundant reduce + ternary quant + gate combine ----
// 144 blocks x 256 thr. Every block computes the SAME f64 sums in the SAME
// fixed order (4 accumulators, fixed combine) -> bitwise-identical scales.
__global__ __launch_bounds__(256) void prep(
    const float* __restrict__ w, const float* __restrict__ wc,
    const float* __restrict__ b, const float* __restrict__ bc,
    const float* __restrict__ gate,
    unsigned short* __restrict__ wq, float* __restrict__ beff) {
  const int tid = threadIdx.x;
  const float4v* w4 = (const float4v*)w;    // 9216 float4
  const float4v* c4 = (const float4v*)wc;
  double a0 = 0, a1 = 0, a2 = 0, a3 = 0;
  double c0 = 0, c1 = 0, c2 = 0, c3 = 0;
#pragma unroll
  for (int i = 0; i < 36; i += 4) {         // batch: 8 float4 loads in flight
    float4v wa = w4[tid + (i + 0) * 256];
    float4v wb = w4[tid + (i + 1) * 256];
    float4v wcv = w4[tid + (i + 2) * 256];
    float4v wd = w4[tid + (i + 3) * 256];
    float4v xa = c4[tid + (i + 0) * 256];
    float4v xb = c4[tid + (i + 1) * 256];
    float4v xc = c4[tid + (i + 2) * 256];
    float4v xd = c4[tid + (i + 3) * 256];
    a0 += (double)fabsf(wa[0]) + (double)fabsf(wa[1]) + (double)fabsf(wa[2]) + (double)fabsf(wa[3]);
    a1 += (double)fabsf(wb[0]) + (double)fabsf(wb[1]) + (double)fabsf(wb[2]) + (double)fabsf(wb[3]);
    a2 += (double)fabsf(wcv[0]) + (double)fabsf(wcv[1]) + (double)fabsf(wcv[2]) + (double)fabsf(wcv[3]);
    a3 += (double)fabsf(wd[0]) + (double)fabsf(wd[1]) + (double)fabsf(wd[2]) + (double)fabsf(wd[3]);
    c0 += (double)fabsf(xa[0]) + (double)fabsf(xa[1]) + (double)fabsf(xa[2]) + (double)fabsf(xa[3]);
    c1 += (double)fabsf(xb[0]) + (double)fabsf(xb[1]) + (double)fabsf(xb[2]) + (double)fabsf(xb[3]);
    c2 += (double)fabsf(xc[0]) + (double)fabsf(xc[1]) + (double)fabsf(xc[2]) + (double)fabsf(xc[3]);
    c3 += (double)fabsf(xd[0]) + (double)fabsf(xd[1]) + (double)fabsf(xd[2]) + (double)fabsf(xd[3]);
  }
  double a = (a0 + a1) + (a2 + a3);
  double c = (c0 + c1) + (c2 + c3);
#pragma unroll
  for (int off = 32; off > 0; off >>= 1) {
    a += __shfl_down(a, off);
    c += __shfl_down(c, off);
  }
  __shared__ double sa[4], sc[4];
  const int wv = tid >> 6;
  if ((tid & 63) == 0) { sa[wv] = a; sc[wv] = c; }
  __syncthreads();
  const double ta = (sa[0] + sa[1]) + (sa[2] + sa[3]);
  const double tc = (sc[0] + sc[1]) + (sc[2] + sc[3]);
  const float sw = fmaxf((float)(ta * (1.0 / 36864.0)), 1e-5f);
  const float scl = fmaxf((float)(tc * (1.0 / 36864.0)), 1e-5f);
  const float g = 1.0f / (1.0f + expf(-gate[0]));
  const int idx = blockIdx.x * 256 + tid;  // (tap, oc, ci)
  const int tap = idx >> 12;
  const int oc = (idx >> 6) & 63;
  const int ci = idx & 63;
  const int src = oc * 576 + ci * 9 + tap;  // OIHW flat
  float q1 = fminf(1.f, fmaxf(-1.f, rintf(w[src] / sw))) * sw;
  float q2 = fminf(1.f, fmaxf(-1.f, rintf(wc[src] / scl))) * scl;
  wq[idx] = f2bf(q1 + g * q2);
  if (idx < 64) beff[idx] = b[idx] + g * bc[idx];
}

// ---- conv: NCHW f32 -> LDS bf16 staging + implicit-GEMM MFMA ----
// Block: 256 thr = 4 waves, 2 output rows x 128 px x 64 oc. Wave = 64px x 64oc.
// LDS 73,728 B -> 2 blocks/CU (147,456 of 163,840):
//   A: 4 rows x 128 interior px x 8 chunks x 16B = 65,536 B;
//      slot (r*128 + px-1)*8 + (c ^ (px&7)); pads px=0/129 via redirect+zero.
//   B: ONE 8,192 B buffer, slot oc*8 + (c ^ (oc&7)). Per tap: read frags,
//      barrier#1 (all reads done), issue B[t+1] global->reg, MFMA (covers
//      L2 latency), ds_write B[t+1], barrier#2. Race-free, 2 barriers/tap.
// XCD-ownership: XCD (bid&7) owns images 2*xcd, 2*xcd+1 (halo stays in 1 L2).
__global__ __launch_bounds__(256, 2) void conv_fused(
    const float* __restrict__ x, const unsigned short* __restrict__ wq,
    const float* __restrict__ beff, float* __restrict__ out) {
  extern __shared__ __align__(16) char smem[];  // 73,728 B
  char* Abase = smem;                  // 4096 chunks
  char* Bbase = smem + 65536;          // 512 chunks

  const int bid = blockIdx.x;          // 1024 blocks
  const int xcd = bid & 7;
  const int u = bid >> 3;              // 0..127
  const int n = xcd * 2 + (u >> 6);    // image
  const int h0 = (u & 63) * 2;         // output rows h0, h0+1
  const int tid = threadIdx.x;
  const int lane = tid & 63;
  const int wv = tid >> 6;             // 0..3
  const int rw = wv >> 1;              // output row within block (0/1)
  const int pxh = (wv & 1) * 64;       // pixel half
  const int ln15 = lane & 15;
  const int lq = lane >> 4;            // 16B ci-chunk (0..3)

  const float* xn = x + (size_t)n * (64 * 16384);

  // ---- B tap-0: 32B/thread coalesced global load (issued early) ----
  const short8 b0a = *(const short8*)(wq + tid * 16);
  const short8 b0b = *(const short8*)(wq + tid * 16 + 8);

  // ---- A staging: 4 groups x {issue 32 loads, then convert+write 4} ----
  const int pxc = tid & 127;           // source col 0..127 (padded px = pxc+1)
  const int hi = tid >> 7;             // 0..1 (wave-uniform)
#pragma unroll
  for (int grp = 0; grp < 4; ++grp) {
    float t[4][8];
#pragma unroll
    for (int j = 0; j < 4; ++j) {      // issue all 32 loads first
      const int k = grp * 8 + j * 2 + hi;  // 0..31
      const int r = k >> 3;            // LDS row 0..3
      const int c = k & 7;             // ci chunk 0..7
      const int h = h0 + r - 1;        // source row, -1..128
      if ((unsigned)h < 128u) {        // wave-uniform
        const float* sp = xn + c * 8 * 16384 + h * 128 + pxc;
#pragma unroll
        for (int e = 0; e < 8; ++e) t[j][e] = sp[e * 16384];
      } else {
#pragma unroll
        for (int e = 0; e < 8; ++e) t[j][e] = 0.f;
      }
    }
#pragma unroll
    for (int j = 0; j < 4; ++j) {      // convert + swizzled ds_write
      const int k = grp * 8 + j * 2 + hi;
      const int r = k >> 3;
      const int c = k & 7;
      short8 v;
#pragma unroll
      for (int e = 0; e < 8; ++e) v[e] = (short)f2bf(t[j][e]);
      const int slot = ((r * 128 + pxc) << 3) + (c ^ ((pxc + 1) & 7));
      *(short8*)(Abase + (slot << 4)) = v;
    }
  }

  // ---- B tap-0 swizzled LDS write (2 chunks/thread) ----
  const int g0 = tid * 2;              // chunk 0..511 (even)
  const int oc0 = g0 >> 3;
  const int c0 = g0 & 7;               // even
  const int bs0 = (oc0 << 3) + (c0 ^ (oc0 & 7));
  const int bs1 = (oc0 << 3) + ((c0 + 1) ^ (oc0 & 7));
  *(short8*)(Bbase + (bs0 << 4)) = b0a;
  *(short8*)(Bbase + (bs1 << 4)) = b0b;
  __syncthreads();

  float4v acc[4][4] = {};  // [mf][qd]

#pragma unroll
  for (int tap = 0; tap < 9; ++tap) {
    const int dh = tap / 3;
    const int dw = tap - dh * 3;
    const int r = rw + dh;             // 0..3
    const int pb = pxh + ln15 + dw;    // padded px for mf=0 (0..81)
    const bool p0 = (pb == 0);         // pad read only at mf=0
    const bool p129 = (pb == 81);      // pad read only at mf=3 (px=129)
    const int a0 = (((r * 128 + pb - 1) << 3) + (lq ^ (pb & 7))) << 4;
    const int off0 = p0 ? 2048 : 0;    // redirect to a valid slot, zeroed below
    const int off3 = p129 ? 4096 : 6144;

    short8 Ab[2][4], Bb[2][4];
#pragma unroll
    for (int cc = 0; cc < 2; ++cc) {   // ci chunk lq vs lq+4: byte addr ^64
      const int ax = a0 ^ (cc << 6);
      Ab[cc][0] = *(const short8*)(Abase + (ax + off0));
      Ab[cc][1] = *(const short8*)(Abase + (ax + 2048));
      Ab[cc][2] = *(const short8*)(Abase + (ax + 4096));
      Ab[cc][3] = *(const short8*)(Abase + (ax + off3));
      if (p0) Ab[cc][0] = (short8)0;
      if (p129) Ab[cc][3] = (short8)0;
    }
#pragma unroll
    for (int qd = 0; qd < 4; ++qd) {
      const int oc8 = ((qd << 4) + ln15) << 3;  // oc*8
      const int k7 = ln15 & 7;                  // oc&7
      Bb[0][qd] = *(const short8*)(Bbase + ((oc8 + (lq ^ k7)) << 4));
      Bb[1][qd] = *(const short8*)(Bbase + ((oc8 + ((lq + 4) ^ k7)) << 4));
    }

    if (tap < 8) __syncthreads();  // barrier#1: all waves done reading B[tap]

    // issue B[t+1] prefetch AFTER barrier#1 (its vmcnt-drain would expose it)
    short8 bta, btb;
    if (tap < 8) {
      bta = *(const short8*)(wq + (tap + 1) * 4096 + tid * 16);
      btb = *(const short8*)(wq + (tap + 1) * 4096 + tid * 16 + 8);
    }

    __builtin_amdgcn_s_setprio(1);
#pragma unroll
    for (int cc2 = 0; cc2 < 2; ++cc2)
#pragma unroll
      for (int mf = 0; mf < 4; ++mf)
#pragma unroll
        for (int qd = 0; qd < 4; ++qd)
          acc[mf][qd] = __builtin_amdgcn_mfma_f32_16x16x32_bf16(
              Ab[cc2][mf], Bb[cc2][qd], acc[mf][qd], 0, 0, 0);
    __builtin_amdgcn_s_setprio(0);

    if (tap < 8) {
      // overwrite the single B buffer (all reads completed at barrier#1;
      // the MFMA cluster covered the prefetch's L2 latency)
      *(short8*)(Bbase + (bs0 << 4)) = bta;
      *(short8*)(Bbase + (bs1 << 4)) = btb;
      __syncthreads();  // barrier#2: B[t+1] visible before next tap's reads
    }
  }

  // ---- epilogue: C/D layout col=lane&15 (oc), row=(lane>>4)*4+reg (pixel) ----
  const int rq = lane >> 4;
  float bias[4];
#pragma unroll
  for (int q = 0; q < 4; ++q) bias[q] = beff[q * 16 + ln15];
#pragma unroll
  for (int mf = 0; mf < 4; ++mf) {
#pragma unroll
    for (int qd = 0; qd < 4; ++qd) {
      float4v v = acc[mf][qd] + bias[qd];
      int oc = qd * 16 + ln15;
      float* op = out + (((n * 64 + oc) * 128 + h0 + rw) * 128 + pxh + mf * 16 + rq * 4);
      *(float4v*)op = v;
    }
  }
}

extern "C" void kernel_launch(void* const* d_in, const int* in_sizes, int n_in,
                              void* d_out, int out_size, void* d_ws, size_t ws_size,
                              hipStream_t stream) {
  const float* x = (const float*)d_in[0];
  const float* w = (const float*)d_in[1];
  const float* b = (const float*)d_in[2];
  const float* wc = (const float*)d_in[3];
  const float* bc = (const float*)d_in[4];
  const float* gate = (const float*)d_in[5];

  // ws: wq bf16[36864]=73728B | beff f32[64] @73728
  unsigned short* wq = (unsigned short*)d_ws;
  float* beff = (float*)((char*)d_ws + 73728);

  prep<<<144, 256, 0, stream>>>(w, wc, b, bc, gate, wq, beff);
  conv_fused<<<1024, 256, 73728, stream>>>(x, wq, beff, (float*)d_out);
}

// Round 8
// 143.178 us; speedup vs baseline: 1.2845x; 1.0055x over previous
//
#include <hip/hip_runtime.h>
#include <math.h>

// ---------------------------------------------------------------------------
// FPSANConv2d: out = conv3x3(x, Qt(w)) + b + sigmoid(gate)*(conv3x3(x, Qt(w_child)) + b_child)
// Fused: W_eff = Qt(w) + g*Qt(w_child) (bf16), b_eff = b + g*b_child, ONE conv.
//
// Round 13: TLP. R10 (8w/1blk) and R12 (4w/2blk) both = 8 waves/CU = 2/SIMD
//   and both ~50us with 70% all-pipes idle -> latency-bound on wave count,
//   not structure. Same tile + LDS + barriers as R12, but 512 thr / 8 waves
//   (wave = 64px x 32oc; split row x pxhalf x ochalf). Peak VGPR ~100 < 128,
//   __launch_bounds__(512,4) -> 2 blocks x 8 waves = 16 waves/CU = 4/SIMD.
//   prep unchanged (R12 fix verified: left top-5).
// ---------------------------------------------------------------------------

typedef __attribute__((ext_vector_type(8))) short short8;   // 8 bf16 (4 VGPRs)
typedef __attribute__((ext_vector_type(4))) float float4v;  // MFMA C/D frag

__device__ inline unsigned short f2bf(float f) {
  union { float f; unsigned u; } v; v.f = f;
  unsigned u = v.u;
  return (unsigned short)((u + 0x7FFFu + ((u >> 16) & 1u)) >> 16);  // RNE
}

// ---- prep: deterministic redundant reduce + ternary quant + gate combine ----
// 144 blocks x 256 thr. Every block computes the SAME f64 sums in the SAME
// fixed order (4 accumulators, fixed combine) -> bitwise-identical scales.
__global__ __launch_bounds__(256) void prep(
    const float* __restrict__ w, const float* __restrict__ wc,
    const float* __restrict__ b, const float* __restrict__ bc,
    const float* __restrict__ gate,
    unsigned short* __restrict__ wq, float* __restrict__ beff) {
  const int tid = threadIdx.x;
  const float4v* w4 = (const float4v*)w;    // 9216 float4
  const float4v* c4 = (const float4v*)wc;
  double a0 = 0, a1 = 0, a2 = 0, a3 = 0;
  double c0 = 0, c1 = 0, c2 = 0, c3 = 0;
#pragma unroll
  for (int i = 0; i < 36; i += 4) {         // batch: 8 float4 loads in flight
    float4v wa = w4[tid + (i + 0) * 256];
    float4v wb = w4[tid + (i + 1) * 256];
    float4v wcv = w4[tid + (i + 2) * 256];
    float4v wd = w4[tid + (i + 3) * 256];
    float4v xa = c4[tid + (i + 0) * 256];
    float4v xb = c4[tid + (i + 1) * 256];
    float4v xc = c4[tid + (i + 2) * 256];
    float4v xd = c4[tid + (i + 3) * 256];
    a0 += (double)fabsf(wa[0]) + (double)fabsf(wa[1]) + (double)fabsf(wa[2]) + (double)fabsf(wa[3]);
    a1 += (double)fabsf(wb[0]) + (double)fabsf(wb[1]) + (double)fabsf(wb[2]) + (double)fabsf(wb[3]);
    a2 += (double)fabsf(wcv[0]) + (double)fabsf(wcv[1]) + (double)fabsf(wcv[2]) + (double)fabsf(wcv[3]);
    a3 += (double)fabsf(wd[0]) + (double)fabsf(wd[1]) + (double)fabsf(wd[2]) + (double)fabsf(wd[3]);
    c0 += (double)fabsf(xa[0]) + (double)fabsf(xa[1]) + (double)fabsf(xa[2]) + (double)fabsf(xa[3]);
    c1 += (double)fabsf(xb[0]) + (double)fabsf(xb[1]) + (double)fabsf(xb[2]) + (double)fabsf(xb[3]);
    c2 += (double)fabsf(xc[0]) + (double)fabsf(xc[1]) + (double)fabsf(xc[2]) + (double)fabsf(xc[3]);
    c3 += (double)fabsf(xd[0]) + (double)fabsf(xd[1]) + (double)fabsf(xd[2]) + (double)fabsf(xd[3]);
  }
  double a = (a0 + a1) + (a2 + a3);
  double c = (c0 + c1) + (c2 + c3);
#pragma unroll
  for (int off = 32; off > 0; off >>= 1) {
    a += __shfl_down(a, off);
    c += __shfl_down(c, off);
  }
  __shared__ double sa[4], sc[4];
  const int wv = tid >> 6;
  if ((tid & 63) == 0) { sa[wv] = a; sc[wv] = c; }
  __syncthreads();
  const double ta = (sa[0] + sa[1]) + (sa[2] + sa[3]);
  const double tc = (sc[0] + sc[1]) + (sc[2] + sc[3]);
  const float sw = fmaxf((float)(ta * (1.0 / 36864.0)), 1e-5f);
  const float scl = fmaxf((float)(tc * (1.0 / 36864.0)), 1e-5f);
  const float g = 1.0f / (1.0f + expf(-gate[0]));
  const int idx = blockIdx.x * 256 + tid;  // (tap, oc, ci)
  const int tap = idx >> 12;
  const int oc = (idx >> 6) & 63;
  const int ci = idx & 63;
  const int src = oc * 576 + ci * 9 + tap;  // OIHW flat
  float q1 = fminf(1.f, fmaxf(-1.f, rintf(w[src] / sw))) * sw;
  float q2 = fminf(1.f, fmaxf(-1.f, rintf(wc[src] / scl))) * scl;
  wq[idx] = f2bf(q1 + g * q2);
  if (idx < 64) beff[idx] = b[idx] + g * bc[idx];
}

// ---- conv: NCHW f32 -> LDS bf16 staging + implicit-GEMM MFMA ----
// Block: 512 thr = 8 waves; tile = 2 output rows x 128 px x 64 oc.
// Wave wv: rw = wv>>2 (row), pxh = ((wv>>1)&1)*64, och = (wv&1)*32.
// Each wave: 64 px x 32 oc -> acc[4][2], 16 MFMAs per tap.
// LDS 73,728 B -> 2 blocks/CU = 16 waves/CU = 4 waves/SIMD:
//   A: 4 rows x 128 interior px x 8 chunks x 16B = 65,536 B;
//      slot (r*128 + px-1)*8 + (c ^ (px&7)); pads px=0/129 via redirect+zero.
//   B: ONE 8,192 B buffer, slot oc*8 + (c ^ (oc&7)). Per tap: read frags,
//      barrier#1, issue B[t+1] global->reg, MFMA (covers L2 latency),
//      ds_write B[t+1], barrier#2. Race-free (R12-verified).
// XCD-ownership: XCD (bid&7) owns images 2*xcd, 2*xcd+1 (halo stays in 1 L2).
__global__ __launch_bounds__(512, 4) void conv_fused(
    const float* __restrict__ x, const unsigned short* __restrict__ wq,
    const float* __restrict__ beff, float* __restrict__ out) {
  extern __shared__ __align__(16) char smem[];  // 73,728 B
  char* Abase = smem;                  // 4096 chunks
  char* Bbase = smem + 65536;          // 512 chunks

  const int bid = blockIdx.x;          // 1024 blocks
  const int xcd = bid & 7;
  const int u = bid >> 3;              // 0..127
  const int n = xcd * 2 + (u >> 6);    // image
  const int h0 = (u & 63) * 2;         // output rows h0, h0+1
  const int tid = threadIdx.x;
  const int lane = tid & 63;
  const int wv = tid >> 6;             // 0..7
  const int rw = wv >> 2;              // output row within block (0/1)
  const int pxh = ((wv >> 1) & 1) * 64;  // pixel half
  const int och = (wv & 1) * 32;       // oc half
  const int ln15 = lane & 15;
  const int lq = lane >> 4;            // 16B ci-chunk (0..3)

  const float* xn = x + (size_t)n * (64 * 16384);

  // ---- B tap-0: 16B/thread coalesced global load (issued early) ----
  const short8 b0v = *(const short8*)(wq + tid * 8);

  // ---- A staging: 2 groups x {issue 32 loads, then convert+write 4} ----
  // 32 (r,c) combos: k = grp*16 + j*4 + hi; hi = tid>>7 (0..3, wave-uniform).
  const int pxc = tid & 127;           // source col 0..127 (padded px = pxc+1)
  const int hi = tid >> 7;             // 0..3 (constant per 2 waves)
#pragma unroll
  for (int grp = 0; grp < 2; ++grp) {
    float t[4][8];
#pragma unroll
    for (int j = 0; j < 4; ++j) {      // issue all 32 loads first
      const int k = grp * 16 + j * 4 + hi;  // 0..31
      const int r = k >> 3;            // LDS row 0..3
      const int c = k & 7;             // ci chunk 0..7
      const int h = h0 + r - 1;        // source row, -1..128
      if ((unsigned)h < 128u) {        // wave-uniform
        const float* sp = xn + c * 8 * 16384 + h * 128 + pxc;
#pragma unroll
        for (int e = 0; e < 8; ++e) t[j][e] = sp[e * 16384];
      } else {
#pragma unroll
        for (int e = 0; e < 8; ++e) t[j][e] = 0.f;
      }
    }
#pragma unroll
    for (int j = 0; j < 4; ++j) {      // convert + swizzled ds_write
      const int k = grp * 16 + j * 4 + hi;
      const int r = k >> 3;
      const int c = k & 7;
      short8 v;
#pragma unroll
      for (int e = 0; e < 8; ++e) v[e] = (short)f2bf(t[j][e]);
      const int slot = ((r * 128 + pxc) << 3) + (c ^ ((pxc + 1) & 7));
      *(short8*)(Abase + (slot << 4)) = v;
    }
  }

  // ---- B tap-0 swizzled LDS write (1 chunk/thread) ----
  const int oc0 = tid >> 3;
  const int c0 = tid & 7;
  const int bs0 = (oc0 << 3) + (c0 ^ (oc0 & 7));
  *(short8*)(Bbase + (bs0 << 4)) = b0v;
  __syncthreads();

  float4v acc[4][2] = {};  // [mf][qd]

#pragma unroll
  for (int tap = 0; tap < 9; ++tap) {
    const int dh = tap / 3;
    const int dw = tap - dh * 3;
    const int r = rw + dh;             // 0..3
    const int pb = pxh + ln15 + dw;    // padded px for mf=0 (0..81)
    const bool p0 = (pb == 0);         // pad read only at mf=0
    const bool p129 = (pb == 81);      // pad read only at mf=3 (px=129)
    const int a0 = (((r * 128 + pb - 1) << 3) + (lq ^ (pb & 7))) << 4;
    const int off0 = p0 ? 2048 : 0;    // redirect to a valid slot, zeroed below
    const int off3 = p129 ? 4096 : 6144;

    short8 Ab[2][4], Bb[2][2];
#pragma unroll
    for (int cc = 0; cc < 2; ++cc) {   // ci chunk lq vs lq+4: byte addr ^64
      const int ax = a0 ^ (cc << 6);
      Ab[cc][0] = *(const short8*)(Abase + (ax + off0));
      Ab[cc][1] = *(const short8*)(Abase + (ax + 2048));
      Ab[cc][2] = *(const short8*)(Abase + (ax + 4096));
      Ab[cc][3] = *(const short8*)(Abase + (ax + off3));
      if (p0) Ab[cc][0] = (short8)0;
      if (p129) Ab[cc][3] = (short8)0;
    }
#pragma unroll
    for (int qd = 0; qd < 2; ++qd) {
      const int oc8 = (och + (qd << 4) + ln15) << 3;  // oc*8
      const int k7 = ln15 & 7;                        // oc&7 (och,qd*16 == 0 mod 8)
      Bb[0][qd] = *(const short8*)(Bbase + ((oc8 + (lq ^ k7)) << 4));
      Bb[1][qd] = *(const short8*)(Bbase + ((oc8 + ((lq + 4) ^ k7)) << 4));
    }

    if (tap < 8) __syncthreads();  // barrier#1: all waves done reading B[tap]

    // issue B[t+1] prefetch AFTER barrier#1 (its vmcnt-drain would expose it)
    short8 btv;
    if (tap < 8) btv = *(const short8*)(wq + (tap + 1) * 4096 + tid * 8);

    __builtin_amdgcn_s_setprio(1);
#pragma unroll
    for (int cc2 = 0; cc2 < 2; ++cc2)
#pragma unroll
      for (int mf = 0; mf < 4; ++mf)
#pragma unroll
        for (int qd = 0; qd < 2; ++qd)
          acc[mf][qd] = __builtin_amdgcn_mfma_f32_16x16x32_bf16(
              Ab[cc2][mf], Bb[cc2][qd], acc[mf][qd], 0, 0, 0);
    __builtin_amdgcn_s_setprio(0);

    if (tap < 8) {
      // overwrite the single B buffer (all reads completed at barrier#1;
      // the MFMA cluster covered the prefetch's L2 latency)
      *(short8*)(Bbase + (bs0 << 4)) = btv;
      __syncthreads();  // barrier#2: B[t+1] visible before next tap's reads
    }
  }

  // ---- epilogue: C/D layout col=lane&15 (oc), row=(lane>>4)*4+reg (pixel) ----
  const int rq = lane >> 4;
  float bias[2];
#pragma unroll
  for (int q = 0; q < 2; ++q) bias[q] = beff[och + q * 16 + ln15];
#pragma unroll
  for (int mf = 0; mf < 4; ++mf) {
#pragma unroll
    for (int qd = 0; qd < 2; ++qd) {
      float4v v = acc[mf][qd] + bias[qd];
      int oc = och + qd * 16 + ln15;
      float* op = out + (((n * 64 + oc) * 128 + h0 + rw) * 128 + pxh + mf * 16 + rq * 4);
      *(float4v*)op = v;
    }
  }
}

extern "C" void kernel_launch(void* const* d_in, const int* in_sizes, int n_in,
                              void* d_out, int out_size, void* d_ws, size_t ws_size,
                              hipStream_t stream) {
  const float* x = (const float*)d_in[0];
  const float* w = (const float*)d_in[1];
  const float* b = (const float*)d_in[2];
  const float* wc = (const float*)d_in[3];
  const float* bc = (const float*)d_in[4];
  const float* gate = (const float*)d_in[5];

  // ws: wq bf16[36864]=73728B | beff f32[64] @73728
  unsigned short* wq = (unsigned short*)d_ws;
  float* beff = (float*)((char*)d_ws + 73728);

  prep<<<144, 256, 0, stream>>>(w, wc, b, bc, gate, wq, beff);
  conv_fused<<<1024, 512, 73728, stream>>>(x, wq, beff, (float*)d_out);
}